// Round 8
// baseline (228.656 us; speedup 1.0000x reference)
//
#include <hip/hip_runtime.h>
#include <hip/hip_bf16.h>

// MultiHeadAttention: B=4, T=2048, DIM=64, H=12. fp32 I/O.
// Flat-reshape semantics: QKV are (8192,768) row-major; attention slices are
// contiguous 131072-elem chunks. Roles: queries = K rows (i), keys = Q rows
// (j), values = V rows, softmax over j.
// Round 15: r14's SWZ swizzle REVERTED (conflicts were bit-identical 6.34e6
// with/without it -> wrong conflict model; it only cost VALU+VGPR, +8us).
// attn re-blocked for LDS bandwidth: 2 waves x 128 thr per block, each wave
// owns 64 i-rows (kf[2][4], Of[2][2] f32x16). Each Q/V LDS tile is now read
// by 2 waves instead of 4 -> total LDS read traffic halves (the dominant
// ~30us term of the 68us kernel). Same verified 32x32 pair-by-construction
// core, one extra unrolled ih loop. qkv/out/vtrans unchanged from r14.

#define DIM 64
#define NH 12
#define HD 768
#define BT 8192
#define TSEQ 2048
#define NSLICE 48
#define SLICE (TSEQ*DIM)

#define LDQ 72   // LDS row stride (ushorts)
#define LDT 72

typedef unsigned short ushort;
typedef __attribute__((ext_vector_type(8))) short bf16x8;
typedef __attribute__((ext_vector_type(4))) short bf16x4;
typedef __attribute__((ext_vector_type(4))) float f32x4;
typedef __attribute__((ext_vector_type(16))) float f32x16;
typedef __attribute__((ext_vector_type(4))) unsigned int uint32x4;

#define SCALE2 0.18033688011112042f   // 0.125 * log2(e)

__device__ __forceinline__ ushort f2b(float f) {
    union { float f; unsigned int i; } v; v.f = f;
    unsigned int x = v.i;
    return (ushort)((x + 0x7fffu + ((x >> 16) & 1u)) >> 16);  // RNE
}

// ---------------- prep: transpose + convert weights ------------------------
// 48 blocks: z = bx/12 (Wq,Wk,Wv,Wo), tile = bx%12.
__global__ __launch_bounds__(256) void prep_w(
    const float* __restrict__ Wq, const float* __restrict__ Wk,
    const float* __restrict__ Wv, const float* __restrict__ Wo,
    ushort* __restrict__ Wt, ushort* __restrict__ Wot)
{
    __shared__ float tile[64][65];
    int bx = blockIdx.x;
    int z = bx / 12, bt = bx % 12;
    const float* __restrict__ IN = (z == 0) ? Wq : (z == 1) ? Wk : (z == 2) ? Wv : Wo;
    int inStride  = (z < 3) ? HD : DIM;
    int outStride = (z < 3) ? DIM : HD;
    int rbase = (z < 3) ? 0 : bt * 64;
    int cbase = (z < 3) ? bt * 64 : 0;
    ushort* __restrict__ OUT = (z < 3) ? (Wt + (size_t)z * HD * DIM) : Wot;
    int t = threadIdx.x;
    int r = t >> 2, c0 = (t & 3) * 16;
    #pragma unroll
    for (int cc = 0; cc < 16; cc += 4) {
        float4 a = *(const float4*)&IN[(size_t)(rbase + r) * inStride + cbase + c0 + cc];
        tile[r][c0 + cc] = a.x; tile[r][c0 + cc + 1] = a.y;
        tile[r][c0 + cc + 2] = a.z; tile[r][c0 + cc + 3] = a.w;
    }
    __syncthreads();
    int cl = t >> 2, r0 = (t & 3) * 16;
    ushort tmp[16] __attribute__((aligned(16)));
    #pragma unroll
    for (int rr = 0; rr < 16; ++rr) tmp[rr] = f2b(tile[r0 + rr][cl]);
    *(float4*)&OUT[(size_t)(cbase + cl) * outStride + rbase + r0] = *(const float4*)tmp;
    *(float4*)&OUT[(size_t)(cbase + cl) * outStride + rbase + r0 + 8] = *(const float4*)&tmp[8];
}

// ---------------- Kernel 1: Q/K/V = x @ W (MFMA; x read as fp32) -----------
// grid (128 row-tiles, 6 col-groups), 256 thr = 4 waves; wave owns 16 rows
// and loops 6 col-tiles. Q written pre-scaled by SCALE2.
__global__ __launch_bounds__(256) void qkv_kernel(
    const float* __restrict__ x, const ushort* __restrict__ Wt,
    ushort* __restrict__ Q, ushort* __restrict__ K, ushort* __restrict__ V)
{
    int rt = blockIdx.x, yg = blockIdx.y;
    int t = threadIdx.x, w = t >> 6, lane = t & 63;
    int ln = lane & 15, q = lane >> 4;
    int m0 = rt * 64 + w * 16;

    // A-frags from fp32 x, converted in-reg (once per wave)
    float4 xa = *(const float4*)&x[(size_t)(m0 + ln) * DIM + q * 8];
    float4 xb_ = *(const float4*)&x[(size_t)(m0 + ln) * DIM + q * 8 + 4];
    float4 xc = *(const float4*)&x[(size_t)(m0 + ln) * DIM + 32 + q * 8];
    float4 xd = *(const float4*)&x[(size_t)(m0 + ln) * DIM + 32 + q * 8 + 4];
    ushort ta[8] __attribute__((aligned(16)));
    ushort tb[8] __attribute__((aligned(16)));
    ta[0]=f2b(xa.x); ta[1]=f2b(xa.y); ta[2]=f2b(xa.z); ta[3]=f2b(xa.w);
    ta[4]=f2b(xb_.x); ta[5]=f2b(xb_.y); ta[6]=f2b(xb_.z); ta[7]=f2b(xb_.w);
    tb[0]=f2b(xc.x); tb[1]=f2b(xc.y); tb[2]=f2b(xc.z); tb[3]=f2b(xc.w);
    tb[4]=f2b(xd.x); tb[5]=f2b(xd.y); tb[6]=f2b(xd.z); tb[7]=f2b(xd.w);
    bf16x8 af0 = *(const bf16x8*)ta;
    bf16x8 af1 = *(const bf16x8*)tb;

    for (int cc = 0; cc < 6; ++cc) {
        int ct = yg * 6 + cc;
        int which = ct / 12;
        int col0 = (ct % 12) * 64;
        const ushort* __restrict__ Wz = Wt + (size_t)which * HD * DIM;  // (768x64)
        ushort* __restrict__ Y = (which == 0) ? Q : (which == 1) ? K : V;
        float sc = (which == 0) ? SCALE2 : 1.f;
        #pragma unroll
        for (int nt = 0; nt < 4; ++nt) {
            int n = col0 + nt * 16 + ln;
            bf16x8 bf0 = *(const bf16x8*)&Wz[(size_t)n * DIM + q * 8];
            bf16x8 bf1 = *(const bf16x8*)&Wz[(size_t)n * DIM + 32 + q * 8];
            f32x4 acc = (f32x4){0.f, 0.f, 0.f, 0.f};
            acc = __builtin_amdgcn_mfma_f32_16x16x32_bf16(af0, bf0, acc, 0, 0, 0);
            acc = __builtin_amdgcn_mfma_f32_16x16x32_bf16(af1, bf1, acc, 0, 0, 0);
            #pragma unroll
            for (int r = 0; r < 4; ++r)
                Y[(size_t)(m0 + q * 4 + r) * HD + col0 + nt * 16 + ln] = f2b(acc[r] * sc);
        }
    }
}

// ---------------- Kernel 1b: Vt[s][d][t] = V[s][t][d] ----------------------
// XOR-swizzled transposed scalar writes (banks spread), vector reads un-swizzle.
__global__ __launch_bounds__(256) void vtrans_kernel(
    const ushort* __restrict__ V, ushort* __restrict__ Vt)
{
    __shared__ ushort tileT[64 * LDT];
    int tt = blockIdx.x, s = blockIdx.y;
    const ushort* __restrict__ Vp = V + (size_t)s * SLICE;
    ushort* __restrict__ Vo = Vt + (size_t)s * SLICE;
    int t = threadIdx.x;
    int r = t >> 3, c = (t & 7) * 8;
    ushort va[8] __attribute__((aligned(16)));
    ushort vb[8] __attribute__((aligned(16)));
    *(float4*)va = *(const float4*)&Vp[(size_t)(tt * 64 + r) * DIM + c];
    *(float4*)vb = *(const float4*)&Vp[(size_t)(tt * 64 + r + 32) * DIM + c];
    int g0 = ((r >> 3) ^ (c >> 3)) * 8 + (r & 7);
    int g1 = (((r + 32) >> 3) ^ (c >> 3)) * 8 + (r & 7);
    #pragma unroll
    for (int k = 0; k < 8; ++k) {
        tileT[(c + k) * LDT + g0] = va[k];
        tileT[(c + k) * LDT + g1] = vb[k];
    }
    __syncthreads();
    #pragma unroll
    for (int j = 0; j < 2; ++j) {
        int flat = t + 256 * j;
        int d = flat >> 3, tg = flat & 7;
        int sg = tg ^ ((d >> 3) & 7);
        float4 vv = *(const float4*)&tileT[d * LDT + sg * 8];
        *(float4*)&Vo[(size_t)d * TSEQ + tt * 64 + tg * 8] = vv;
    }
}

// ---------------- Kernel 2: MFMA flash attention (32x32, 64 i/wave) --------
// grid (16 i-tiles, 48 slices), 128 thr = 2 waves; wave owns 64 i-rows
// (ih=0,1 halves of 32). Each Q/V LDS tile read by only 2 waves (was 4).
// S^T via mfma_32x32x16 (A=Q rows j, B=K rows i): lane (hi,i5) holds, for
// column i=i5(+32ih), acc reg r = row j=(r&3)+8*(r>>2)+4hi. exp2+trunc-pack
// in reg order; PV B-operand loads V^T rows in the same j pattern
// (pair-by-construction). Single barrier per j-tile, reg-prefetch dbuf.
__global__ __launch_bounds__(128, 2) void attn_kernel(
    const ushort* __restrict__ Qs, const ushort* __restrict__ Ks,
    const ushort* __restrict__ Vts, ushort* __restrict__ Zs)
{
    __shared__ ushort sh[4 * 64 * LDQ];   // [Qt0][Qt1][Vt0][Vt1]; epilogue reuses
    int itile = blockIdx.x, s = blockIdx.y;
    const ushort* __restrict__ Qp = Qs + (size_t)s * SLICE;
    const ushort* __restrict__ Kp = Ks + (size_t)s * SLICE;
    const ushort* __restrict__ Vp = Vts + (size_t)s * SLICE;   // [64][2048]
    ushort* __restrict__ Zp = Zs + (size_t)s * SLICE;
    int t = threadIdx.x, w = t >> 6, lane = t & 63;
    int i5 = lane & 31, hi = lane >> 5;

    // K fragments (B-operand): i = itile*128 + w*64 + ih*32 + i5
    bf16x8 kf[2][4];
    #pragma unroll
    for (int ih = 0; ih < 2; ++ih) {
        size_t krow = (size_t)(itile * 128 + w * 64 + ih * 32 + i5) * DIM;
        #pragma unroll
        for (int c = 0; c < 4; ++c)
            kf[ih][c] = *(const bf16x8*)&Kp[krow + c * 16 + hi * 8];
    }

    f32x16 Of[2][2];   // [ih][dt], all indices compile-time after unroll
    #pragma unroll
    for (int ih = 0; ih < 2; ++ih)
        #pragma unroll
        for (int dt = 0; dt < 2; ++dt)
            #pragma unroll
            for (int r = 0; r < 16; ++r) Of[ih][dt][r] = 0.f;
    float lsum[2] = {0.f, 0.f};

    int sr = t >> 3, sc = (t & 7) * 8;   // sr 0..15; 4 rows per thread
    // prologue: tile 0 -> buf 0, prefetch tile 1 into regs
    float4 qa[4], va[4];
    #pragma unroll
    for (int k = 0; k < 4; ++k) {
        qa[k] = *(const float4*)&Qp[(size_t)(sr + 16 * k) * DIM + sc];
        va[k] = *(const float4*)&Vp[(size_t)(sr + 16 * k) * TSEQ + sc];
    }
    {
        ushort* Q0 = sh;
        ushort* V0 = sh + 2 * 64 * LDQ;
        #pragma unroll
        for (int k = 0; k < 4; ++k) {
            *(float4*)&Q0[(sr + 16 * k) * LDQ + sc] = qa[k];
            *(float4*)&V0[(sr + 16 * k) * LDQ + sc] = va[k];
        }
    }
    #pragma unroll
    for (int k = 0; k < 4; ++k) {
        qa[k] = *(const float4*)&Qp[(size_t)(64 + sr + 16 * k) * DIM + sc];
        va[k] = *(const float4*)&Vp[(size_t)(sr + 16 * k) * TSEQ + 64 + sc];
    }
    __syncthreads();

    for (int tt = 0; tt < 32; ++tt) {
        int ib = tt & 1;
        const ushort* Qc = sh + ib * (64 * LDQ);
        const ushort* Vc = sh + (2 + ib) * (64 * LDQ);
        // stage next tile into the other buffer; issue loads for tile tt+2
        if (tt < 31) {
            ushort* Qn = sh + (ib ^ 1) * (64 * LDQ);
            ushort* Vn = sh + (2 + (ib ^ 1)) * (64 * LDQ);
            #pragma unroll
            for (int k = 0; k < 4; ++k) {
                *(float4*)&Qn[(sr + 16 * k) * LDQ + sc] = qa[k];
                *(float4*)&Vn[(sr + 16 * k) * LDQ + sc] = va[k];
            }
            if (tt < 30) {
                size_t qo = (size_t)(tt + 2) * 64 * DIM;
                int vo = (tt + 2) * 64;
                #pragma unroll
                for (int k = 0; k < 4; ++k) {
                    qa[k] = *(const float4*)&Qp[(size_t)(sr + 16 * k) * DIM + qo + sc];
                    va[k] = *(const float4*)&Vp[(size_t)(sr + 16 * k) * TSEQ + vo + sc];
                }
            }
        }
        #pragma unroll
        for (int js = 0; js < 2; ++js) {
            // Q fragments read ONCE, shared across both ih halves
            bf16x8 aQ[4];
            #pragma unroll
            for (int c = 0; c < 4; ++c)
                aQ[c] = *(const bf16x8*)&Qc[(js * 32 + i5) * LDQ + c * 16 + hi * 8];
            // S^T (32j x 32i) per ih half, Q pre-scaled (log2-units)
            f32x16 acc[2];
            #pragma unroll
            for (int ih = 0; ih < 2; ++ih) {
                #pragma unroll
                for (int r = 0; r < 16; ++r) acc[ih][r] = 0.f;
                #pragma unroll
                for (int c = 0; c < 4; ++c)
                    acc[ih] = __builtin_amdgcn_mfma_f32_32x32x16_bf16(aQ[c], kf[ih][c], acc[ih], 0, 0, 0);
            }
            // p = exp2(S); truncation-pack; l from truncated values
            bf16x8 pa[2][2];
            #pragma unroll
            for (int ih = 0; ih < 2; ++ih) {
                unsigned wv[8];
                float ls = 0.f;
                #pragma unroll
                for (int k = 0; k < 8; ++k) {
                    float p0 = __builtin_amdgcn_exp2f(acc[ih][2 * k]);
                    float p1 = __builtin_amdgcn_exp2f(acc[ih][2 * k + 1]);
                    unsigned int b0 = __float_as_uint(p0), b1 = __float_as_uint(p1);
                    unsigned int t1 = b1 & 0xFFFF0000u;
                    unsigned int h = (b0 >> 16) | t1;
                    ls += __uint_as_float(h << 16) + __uint_as_float(t1);
                    wv[k] = h;
                }
                lsum[ih] += ls;
                uint32x4 u0 = { wv[0], wv[1], wv[2], wv[3] };
                uint32x4 u1 = { wv[4], wv[5], wv[6], wv[7] };
                pa[ih][0] = __builtin_bit_cast(bf16x8, u0);
                pa[ih][1] = __builtin_bit_cast(bf16x8, u1);
            }
            // Z += P * V: V fragments read once per (js,dt), shared across ih
            #pragma unroll
            for (int dt = 0; dt < 2; ++dt) {
                int vbase = (dt * 32 + i5) * LDQ + js * 32 + 4 * hi;
                bf16x4 v0a = *(const bf16x4*)&Vc[vbase];
                bf16x4 v0b = *(const bf16x4*)&Vc[vbase + 8];
                bf16x4 v1a = *(const bf16x4*)&Vc[vbase + 16];
                bf16x4 v1b = *(const bf16x4*)&Vc[vbase + 24];
                bf16x8 vb0 = __builtin_shufflevector(v0a, v0b, 0, 1, 2, 3, 4, 5, 6, 7);
                bf16x8 vb1 = __builtin_shufflevector(v1a, v1b, 0, 1, 2, 3, 4, 5, 6, 7);
                #pragma unroll
                for (int ih = 0; ih < 2; ++ih) {
                    Of[ih][dt] = __builtin_amdgcn_mfma_f32_32x32x16_bf16(pa[ih][0], vb0, Of[ih][dt], 0, 0, 0);
                    Of[ih][dt] = __builtin_amdgcn_mfma_f32_32x32x16_bf16(pa[ih][1], vb1, Of[ih][dt], 0, 0, 0);
                }
            }
        }
        __syncthreads();
    }

    // l per ih-half: partner lane (hi^1) holds complementary j's for same i
    #pragma unroll
    for (int ih = 0; ih < 2; ++ih) {
        float l = lsum[ih] + __shfl_xor(lsum[ih], 32);
        float linv = 1.f / l;
        #pragma unroll
        for (int r = 0; r < 16; ++r) {
            int cr = (r & 3) + 8 * (r >> 2);
            float li = __shfl(linv, cr + 4 * hi);
            int row = w * 64 + ih * 32 + cr + 4 * hi;
            sh[row * LDQ + i5]      = f2b(Of[ih][0][r] * li);
            sh[row * LDQ + 32 + i5] = f2b(Of[ih][1][r] * li);
        }
    }
    __syncthreads();
    #pragma unroll
    for (int p = 0; p < 2; ++p) {
        int zr = p * 64 + (t >> 1), zc = (t & 1) * 32;
        size_t zoff = (size_t)(itile * 128 + zr) * DIM + zc;
        #pragma unroll
        for (int c4 = 0; c4 < 4; ++c4)
            *(float4*)&Zp[zoff + c4 * 8] = *(const float4*)&sh[zr * LDQ + zc + c4 * 8];
    }
}

// ---------------- Kernel 3: out = Z @ Wo (MFMA, fp32 out) ------------------
// M=8192, N=64, K=768. 128 blocks x 4 INDEPENDENT waves (no shared state):
// wave w owns rows bx*64 + w*16, full K loop.
__global__ __launch_bounds__(256) void out_kernel(
    const ushort* __restrict__ Z, const ushort* __restrict__ Wot,
    float* __restrict__ out)
{
    int t = threadIdx.x, w = t >> 6, lane = t & 63;
    int m0 = blockIdx.x * 64 + w * 16;
    int ln = lane & 15, q = lane >> 4;
    f32x4 acc[4];
    #pragma unroll
    for (int nt = 0; nt < 4; ++nt) acc[nt] = (f32x4){0.f, 0.f, 0.f, 0.f};
    for (int kc = 0; kc < 24; ++kc) {
        bf16x8 a = *(const bf16x8*)&Z[(size_t)(m0 + ln) * HD + kc * 32 + q * 8];
        #pragma unroll
        for (int nt = 0; nt < 4; ++nt) {
            bf16x8 bf = *(const bf16x8*)&Wot[(size_t)(nt * 16 + ln) * HD + kc * 32 + q * 8];
            acc[nt] = __builtin_amdgcn_mfma_f32_16x16x32_bf16(a, bf, acc[nt], 0, 0, 0);
        }
    }
    #pragma unroll
    for (int nt = 0; nt < 4; ++nt)
        #pragma unroll
        for (int r = 0; r < 4; ++r)
            out[(size_t)(m0 + q * 4 + r) * DIM + nt * 16 + ln] = acc[nt][r];
}

extern "C" void kernel_launch(void* const* d_in, const int* in_sizes, int n_in,
                              void* d_out, int out_size, void* d_ws, size_t ws_size,
                              hipStream_t stream)
{
    const float* x  = (const float*)d_in[0];
    const float* Wq = (const float*)d_in[1];
    const float* Wk = (const float*)d_in[2];
    const float* Wv = (const float*)d_in[3];
    const float* Wo = (const float*)d_in[4];
    float* out = (float*)d_out;

    const size_t n = (size_t)BT * HD;            // 6,291,456
    ushort* Q   = (ushort*)d_ws;
    ushort* K   = Q + n;
    ushort* V   = K + n;                         // Z aliases V (V dead after vtrans)
    ushort* Vt  = V + n;
    ushort* Wt  = Vt;                            // Wt lives only until qkv done;
    ushort* Wot = Vt + n;                        //   then vtrans overwrites with Vt
    ushort* Z   = V;

    prep_w<<<48, 256, 0, stream>>>(Wq, Wk, Wv, Wo, Wt, Wot);
    qkv_kernel<<<dim3(128, 6), 256, 0, stream>>>(x, Wt, Q, K, V);
    vtrans_kernel<<<dim3(32, 48), 256, 0, stream>>>(V, Vt);
    attn_kernel<<<dim3(16, 48), 128, 0, stream>>>(Q, K, Vt, Z);
    out_kernel<<<128, 256, 0, stream>>>(Z, Wot, out);
}

// Round 9
// 179.728 us; speedup vs baseline: 1.2722x; 1.2722x over previous
//
#include <hip/hip_runtime.h>
#include <hip/hip_bf16.h>

// MultiHeadAttention: B=4, T=2048, DIM=64, H=12. fp32 I/O.
// Flat-reshape semantics: QKV are (8192,768) row-major; attention slices are
// contiguous 131072-elem chunks. Roles: queries = K rows (i), keys = Q rows
// (j), values = V rows, softmax over j.
// Round 17: r15's 64-i/wave REVERTED (register spill: WRITE_SIZE 12->205MB).
// Back to the verified r13 attn core (4 waves, 32 i/wave, VGPR 64) with ONE
// attn change: l computed via MFMA against an all-ones B-fragment instead of
// VALU accumulation. Deletes 3 VALU ops/pair + the final shfl reduction
// (VALU was the top pipe at 43%); adds 4 MFMA/iter on the 31%-busy pipe.
// L[r] lands at exactly the row Of[r] normalizes (same D-map) -> no shfls.
// Plus: qkv split y=12 (6 waves/SIMD), out_kernel 128x256 independent waves.

#define DIM 64
#define NH 12
#define HD 768
#define BT 8192
#define TSEQ 2048
#define NSLICE 48
#define SLICE (TSEQ*DIM)

#define LDQ 72   // LDS row stride (ushorts)
#define LDT 72

typedef unsigned short ushort;
typedef __attribute__((ext_vector_type(8))) short bf16x8;
typedef __attribute__((ext_vector_type(4))) short bf16x4;
typedef __attribute__((ext_vector_type(4))) float f32x4;
typedef __attribute__((ext_vector_type(16))) float f32x16;
typedef __attribute__((ext_vector_type(4))) unsigned int uint32x4;

#define SCALE2 0.18033688011112042f   // 0.125 * log2(e)

__device__ __forceinline__ ushort f2b(float f) {
    union { float f; unsigned int i; } v; v.f = f;
    unsigned int x = v.i;
    return (ushort)((x + 0x7fffu + ((x >> 16) & 1u)) >> 16);  // RNE
}

// ---------------- prep: transpose + convert weights ------------------------
// 48 blocks: z = bx/12 (Wq,Wk,Wv,Wo), tile = bx%12.
__global__ __launch_bounds__(256) void prep_w(
    const float* __restrict__ Wq, const float* __restrict__ Wk,
    const float* __restrict__ Wv, const float* __restrict__ Wo,
    ushort* __restrict__ Wt, ushort* __restrict__ Wot)
{
    __shared__ float tile[64][65];
    int bx = blockIdx.x;
    int z = bx / 12, bt = bx % 12;
    const float* __restrict__ IN = (z == 0) ? Wq : (z == 1) ? Wk : (z == 2) ? Wv : Wo;
    int inStride  = (z < 3) ? HD : DIM;
    int outStride = (z < 3) ? DIM : HD;
    int rbase = (z < 3) ? 0 : bt * 64;
    int cbase = (z < 3) ? bt * 64 : 0;
    ushort* __restrict__ OUT = (z < 3) ? (Wt + (size_t)z * HD * DIM) : Wot;
    int t = threadIdx.x;
    int r = t >> 2, c0 = (t & 3) * 16;
    #pragma unroll
    for (int cc = 0; cc < 16; cc += 4) {
        float4 a = *(const float4*)&IN[(size_t)(rbase + r) * inStride + cbase + c0 + cc];
        tile[r][c0 + cc] = a.x; tile[r][c0 + cc + 1] = a.y;
        tile[r][c0 + cc + 2] = a.z; tile[r][c0 + cc + 3] = a.w;
    }
    __syncthreads();
    int cl = t >> 2, r0 = (t & 3) * 16;
    ushort tmp[16] __attribute__((aligned(16)));
    #pragma unroll
    for (int rr = 0; rr < 16; ++rr) tmp[rr] = f2b(tile[r0 + rr][cl]);
    *(float4*)&OUT[(size_t)(cbase + cl) * outStride + rbase + r0] = *(const float4*)tmp;
    *(float4*)&OUT[(size_t)(cbase + cl) * outStride + rbase + r0 + 8] = *(const float4*)&tmp[8];
}

// ---------------- Kernel 1: Q/K/V = x @ W (MFMA; x read as fp32) -----------
// grid (128 row-tiles, 12 col-groups), 256 thr = 4 waves; wave owns 16 rows
// and loops 3 col-tiles (6144 waves = 6/SIMD). Q written pre-scaled by SCALE2.
__global__ __launch_bounds__(256) void qkv_kernel(
    const float* __restrict__ x, const ushort* __restrict__ Wt,
    ushort* __restrict__ Q, ushort* __restrict__ K, ushort* __restrict__ V)
{
    int rt = blockIdx.x, yg = blockIdx.y;
    int t = threadIdx.x, w = t >> 6, lane = t & 63;
    int ln = lane & 15, q = lane >> 4;
    int m0 = rt * 64 + w * 16;

    // A-frags from fp32 x, converted in-reg (once per wave)
    float4 xa = *(const float4*)&x[(size_t)(m0 + ln) * DIM + q * 8];
    float4 xb_ = *(const float4*)&x[(size_t)(m0 + ln) * DIM + q * 8 + 4];
    float4 xc = *(const float4*)&x[(size_t)(m0 + ln) * DIM + 32 + q * 8];
    float4 xd = *(const float4*)&x[(size_t)(m0 + ln) * DIM + 32 + q * 8 + 4];
    ushort ta[8] __attribute__((aligned(16)));
    ushort tb[8] __attribute__((aligned(16)));
    ta[0]=f2b(xa.x); ta[1]=f2b(xa.y); ta[2]=f2b(xa.z); ta[3]=f2b(xa.w);
    ta[4]=f2b(xb_.x); ta[5]=f2b(xb_.y); ta[6]=f2b(xb_.z); ta[7]=f2b(xb_.w);
    tb[0]=f2b(xc.x); tb[1]=f2b(xc.y); tb[2]=f2b(xc.z); tb[3]=f2b(xc.w);
    tb[4]=f2b(xd.x); tb[5]=f2b(xd.y); tb[6]=f2b(xd.z); tb[7]=f2b(xd.w);
    bf16x8 af0 = *(const bf16x8*)ta;
    bf16x8 af1 = *(const bf16x8*)tb;

    for (int cc = 0; cc < 3; ++cc) {
        int ct = yg * 3 + cc;
        int which = ct / 12;
        int col0 = (ct % 12) * 64;
        const ushort* __restrict__ Wz = Wt + (size_t)which * HD * DIM;  // (768x64)
        ushort* __restrict__ Y = (which == 0) ? Q : (which == 1) ? K : V;
        float sc = (which == 0) ? SCALE2 : 1.f;
        #pragma unroll
        for (int nt = 0; nt < 4; ++nt) {
            int n = col0 + nt * 16 + ln;
            bf16x8 bf0 = *(const bf16x8*)&Wz[(size_t)n * DIM + q * 8];
            bf16x8 bf1 = *(const bf16x8*)&Wz[(size_t)n * DIM + 32 + q * 8];
            f32x4 acc = (f32x4){0.f, 0.f, 0.f, 0.f};
            acc = __builtin_amdgcn_mfma_f32_16x16x32_bf16(af0, bf0, acc, 0, 0, 0);
            acc = __builtin_amdgcn_mfma_f32_16x16x32_bf16(af1, bf1, acc, 0, 0, 0);
            #pragma unroll
            for (int r = 0; r < 4; ++r)
                Y[(size_t)(m0 + q * 4 + r) * HD + col0 + nt * 16 + ln] = f2b(acc[r] * sc);
        }
    }
}

// ---------------- Kernel 1b: Vt[s][d][t] = V[s][t][d] ----------------------
// XOR-swizzled transposed scalar writes (banks spread), vector reads un-swizzle.
__global__ __launch_bounds__(256) void vtrans_kernel(
    const ushort* __restrict__ V, ushort* __restrict__ Vt)
{
    __shared__ ushort tileT[64 * LDT];
    int tt = blockIdx.x, s = blockIdx.y;
    const ushort* __restrict__ Vp = V + (size_t)s * SLICE;
    ushort* __restrict__ Vo = Vt + (size_t)s * SLICE;
    int t = threadIdx.x;
    int r = t >> 3, c = (t & 7) * 8;
    ushort va[8] __attribute__((aligned(16)));
    ushort vb[8] __attribute__((aligned(16)));
    *(float4*)va = *(const float4*)&Vp[(size_t)(tt * 64 + r) * DIM + c];
    *(float4*)vb = *(const float4*)&Vp[(size_t)(tt * 64 + r + 32) * DIM + c];
    int g0 = ((r >> 3) ^ (c >> 3)) * 8 + (r & 7);
    int g1 = (((r + 32) >> 3) ^ (c >> 3)) * 8 + (r & 7);
    #pragma unroll
    for (int k = 0; k < 8; ++k) {
        tileT[(c + k) * LDT + g0] = va[k];
        tileT[(c + k) * LDT + g1] = vb[k];
    }
    __syncthreads();
    #pragma unroll
    for (int j = 0; j < 2; ++j) {
        int flat = t + 256 * j;
        int d = flat >> 3, tg = flat & 7;
        int sg = tg ^ ((d >> 3) & 7);
        float4 vv = *(const float4*)&tileT[d * LDT + sg * 8];
        *(float4*)&Vo[(size_t)d * TSEQ + tt * 64 + tg * 8] = vv;
    }
}

// ---------------- Kernel 2: MFMA flash attention (32x32, reg-P, dbuf) ------
// r13 core: grid (16 i-tiles, 48 slices), 256 thr = 4 waves; wave owns 32
// i-rows. S^T via mfma_32x32x16; acc reg r <-> j=(r&3)+8*(r>>2)+4hi
// [m74/m101 D-map, HW-verified r13]. exp2+truncation-pack in reg order; PV
// B-operand loads V^T rows in the same j pattern (pair-by-construction).
// NEW: l via MFMA with all-ones B (correct under any k-map since B is
// k-uniform); L[r] lands at row cr+4hi = the row Of[r] normalizes -> the
// lsum VALU chain, shfl_xor and shfl broadcasts are deleted.
__global__ __launch_bounds__(256, 3) void attn_kernel(
    const ushort* __restrict__ Qs, const ushort* __restrict__ Ks,
    const ushort* __restrict__ Vts, ushort* __restrict__ Zs)
{
    __shared__ ushort sh[4 * 64 * LDQ];   // [Qt0][Qt1][Vt0][Vt1]; epilogue reuses
    int itile = blockIdx.x, s = blockIdx.y;
    const ushort* __restrict__ Qp = Qs + (size_t)s * SLICE;
    const ushort* __restrict__ Kp = Ks + (size_t)s * SLICE;
    const ushort* __restrict__ Vp = Vts + (size_t)s * SLICE;   // [64][2048]
    ushort* __restrict__ Zp = Zs + (size_t)s * SLICE;
    int t = threadIdx.x, w = t >> 6, lane = t & 63;
    int i5 = lane & 31, hi = lane >> 5;

    // K fragments (B-operand): lane holds K[i0+i5][c*16 + hi*8 + e]
    bf16x8 kf[4];
    {
        size_t krow = (size_t)(itile * 128 + w * 32 + i5) * DIM;
        #pragma unroll
        for (int c = 0; c < 4; ++c)
            kf[c] = *(const bf16x8*)&Kp[krow + c * 16 + hi * 8];
    }
    // all-ones bf16 B-fragment for the l-reduction MFMA
    const uint32x4 uones = { 0x3F803F80u, 0x3F803F80u, 0x3F803F80u, 0x3F803F80u };
    const bf16x8 ones = __builtin_bit_cast(bf16x8, uones);

    f32x16 Of0, Of1, Lf;
    #pragma unroll
    for (int r = 0; r < 16; ++r) { Of0[r] = 0.f; Of1[r] = 0.f; Lf[r] = 0.f; }

    int sr = t >> 3, sc = (t & 7) * 8;
    const ushort* qsrc0 = &Qp[(size_t)sr * DIM + sc];
    const ushort* qsrc1 = &Qp[(size_t)(sr + 32) * DIM + sc];
    const ushort* vsrc0 = &Vp[(size_t)sr * TSEQ + sc];
    const ushort* vsrc1 = &Vp[(size_t)(sr + 32) * TSEQ + sc];

    // prologue: tile 0 -> buf 0, prefetch tile 1 into regs
    float4 qa0 = *(const float4*)qsrc0;
    float4 qa1 = *(const float4*)qsrc1;
    float4 va0 = *(const float4*)vsrc0;
    float4 va1 = *(const float4*)vsrc1;
    *(float4*)&sh[sr * LDQ + sc] = qa0;
    *(float4*)&sh[(sr + 32) * LDQ + sc] = qa1;
    *(float4*)&sh[2 * 64 * LDQ + sr * LDQ + sc] = va0;
    *(float4*)&sh[2 * 64 * LDQ + (sr + 32) * LDQ + sc] = va1;
    qa0 = *(const float4*)(qsrc0 + 64 * DIM);
    qa1 = *(const float4*)(qsrc1 + 64 * DIM);
    va0 = *(const float4*)(vsrc0 + 64);
    va1 = *(const float4*)(vsrc1 + 64);
    __syncthreads();

    for (int tt = 0; tt < 32; ++tt) {
        int ib = tt & 1;
        const ushort* Qc = sh + ib * (64 * LDQ);
        const ushort* Vc = sh + (2 + ib) * (64 * LDQ);
        // stage next tile into the other buffer; issue loads for tile tt+2
        if (tt < 31) {
            ushort* Qn = sh + (ib ^ 1) * (64 * LDQ);
            ushort* Vn = sh + (2 + (ib ^ 1)) * (64 * LDQ);
            *(float4*)&Qn[sr * LDQ + sc] = qa0;
            *(float4*)&Qn[(sr + 32) * LDQ + sc] = qa1;
            *(float4*)&Vn[sr * LDQ + sc] = va0;
            *(float4*)&Vn[(sr + 32) * LDQ + sc] = va1;
            if (tt < 30) {
                size_t qo = (size_t)(tt + 2) * 64 * DIM;
                int vo = (tt + 2) * 64;
                qa0 = *(const float4*)(qsrc0 + qo);
                qa1 = *(const float4*)(qsrc1 + qo);
                va0 = *(const float4*)(vsrc0 + vo);
                va1 = *(const float4*)(vsrc1 + vo);
            }
        }
        #pragma unroll
        for (int js = 0; js < 2; ++js) {
            // S^T (32j x 32i), Q pre-scaled: S already in log2-units
            f32x16 acc;
            #pragma unroll
            for (int r = 0; r < 16; ++r) acc[r] = 0.f;
            #pragma unroll
            for (int c = 0; c < 4; ++c) {
                bf16x8 aQ = *(const bf16x8*)&Qc[(js * 32 + i5) * LDQ + c * 16 + hi * 8];
                acc = __builtin_amdgcn_mfma_f32_32x32x16_bf16(aQ, kf[c], acc, 0, 0, 0);
            }
            // p = exp2(S); truncation-pack pairs (low short = even reg)
            unsigned wv[8];
            #pragma unroll
            for (int k = 0; k < 8; ++k) {
                float p0 = __builtin_amdgcn_exp2f(acc[2 * k]);
                float p1 = __builtin_amdgcn_exp2f(acc[2 * k + 1]);
                wv[k] = (__float_as_uint(p0) >> 16) | (__float_as_uint(p1) & 0xFFFF0000u);
            }
            uint32x4 u0 = { wv[0], wv[1], wv[2], wv[3] };  // regs 0..7  -> j=(e&3)+8*(e>>2)+4hi
            uint32x4 u1 = { wv[4], wv[5], wv[6], wv[7] };  // regs 8..15 -> j=16+...
            bf16x8 pa0 = __builtin_bit_cast(bf16x8, u0);
            bf16x8 pa1 = __builtin_bit_cast(bf16x8, u1);
            // l += P^T 1 on the matrix pipe (B k-uniform -> k-map agnostic)
            Lf = __builtin_amdgcn_mfma_f32_32x32x16_bf16(pa0, ones, Lf, 0, 0, 0);
            Lf = __builtin_amdgcn_mfma_f32_32x32x16_bf16(pa1, ones, Lf, 0, 0, 0);
            // Z += P * V: B slot (hi,e) loads V^T row j matching pa's reg order
            #pragma unroll
            for (int dt = 0; dt < 2; ++dt) {
                int vbase = (dt * 32 + i5) * LDQ + js * 32 + 4 * hi;
                bf16x4 v0a = *(const bf16x4*)&Vc[vbase];
                bf16x4 v0b = *(const bf16x4*)&Vc[vbase + 8];
                bf16x4 v1a = *(const bf16x4*)&Vc[vbase + 16];
                bf16x4 v1b = *(const bf16x4*)&Vc[vbase + 24];
                bf16x8 vb0 = __builtin_shufflevector(v0a, v0b, 0, 1, 2, 3, 4, 5, 6, 7);
                bf16x8 vb1 = __builtin_shufflevector(v1a, v1b, 0, 1, 2, 3, 4, 5, 6, 7);
                if (dt == 0) {
                    Of0 = __builtin_amdgcn_mfma_f32_32x32x16_bf16(pa0, vb0, Of0, 0, 0, 0);
                    Of0 = __builtin_amdgcn_mfma_f32_32x32x16_bf16(pa1, vb1, Of0, 0, 0, 0);
                } else {
                    Of1 = __builtin_amdgcn_mfma_f32_32x32x16_bf16(pa0, vb0, Of1, 0, 0, 0);
                    Of1 = __builtin_amdgcn_mfma_f32_32x32x16_bf16(pa1, vb1, Of1, 0, 0, 0);
                }
            }
        }
        __syncthreads();
    }

    // normalize: Lf[r] holds l for row cr+4hi (all cols equal) — no shfls
    #pragma unroll
    for (int r = 0; r < 16; ++r) {
        int cr = (r & 3) + 8 * (r >> 2);
        float li = 1.f / Lf[r];
        int row = w * 32 + cr + 4 * hi;
        sh[row * LDQ + i5]      = f2b(Of0[r] * li);
        sh[row * LDQ + 32 + i5] = f2b(Of1[r] * li);
    }
    __syncthreads();
    int zr = t >> 1, zc = (t & 1) * 32;
    size_t zoff = (size_t)(itile * 128 + zr) * DIM + zc;
    #pragma unroll
    for (int c4 = 0; c4 < 4; ++c4)
        *(float4*)&Zp[zoff + c4 * 8] = *(const float4*)&sh[zr * LDQ + zc + c4 * 8];
}

// ---------------- Kernel 3: out = Z @ Wo (MFMA, fp32 out) ------------------
// M=8192, N=64, K=768. 128 blocks x 4 INDEPENDENT waves (no shared state):
// wave w owns rows bx*64 + w*16, full K loop. (passed r14/r15)
__global__ __launch_bounds__(256) void out_kernel(
    const ushort* __restrict__ Z, const ushort* __restrict__ Wot,
    float* __restrict__ out)
{
    int t = threadIdx.x, w = t >> 6, lane = t & 63;
    int m0 = blockIdx.x * 64 + w * 16;
    int ln = lane & 15, q = lane >> 4;
    f32x4 acc[4];
    #pragma unroll
    for (int nt = 0; nt < 4; ++nt) acc[nt] = (f32x4){0.f, 0.f, 0.f, 0.f};
    for (int kc = 0; kc < 24; ++kc) {
        bf16x8 a = *(const bf16x8*)&Z[(size_t)(m0 + ln) * HD + kc * 32 + q * 8];
        #pragma unroll
        for (int nt = 0; nt < 4; ++nt) {
            bf16x8 bf = *(const bf16x8*)&Wot[(size_t)(nt * 16 + ln) * HD + kc * 32 + q * 8];
            acc[nt] = __builtin_amdgcn_mfma_f32_16x16x32_bf16(a, bf, acc[nt], 0, 0, 0);
        }
    }
    #pragma unroll
    for (int nt = 0; nt < 4; ++nt)
        #pragma unroll
        for (int r = 0; r < 4; ++r)
            out[(size_t)(m0 + q * 4 + r) * DIM + nt * 16 + ln] = acc[nt][r];
}

extern "C" void kernel_launch(void* const* d_in, const int* in_sizes, int n_in,
                              void* d_out, int out_size, void* d_ws, size_t ws_size,
                              hipStream_t stream)
{
    const float* x  = (const float*)d_in[0];
    const float* Wq = (const float*)d_in[1];
    const float* Wk = (const float*)d_in[2];
    const float* Wv = (const float*)d_in[3];
    const float* Wo = (const float*)d_in[4];
    float* out = (float*)d_out;

    const size_t n = (size_t)BT * HD;            // 6,291,456
    ushort* Q   = (ushort*)d_ws;
    ushort* K   = Q + n;
    ushort* V   = K + n;                         // Z aliases V (V dead after vtrans)
    ushort* Vt  = V + n;
    ushort* Wt  = Vt;                            // Wt lives only until qkv done;
    ushort* Wot = Vt + n;                        //   then vtrans overwrites with Vt
    ushort* Z   = V;

    prep_w<<<48, 256, 0, stream>>>(Wq, Wk, Wv, Wo, Wt, Wot);
    qkv_kernel<<<dim3(128, 12), 256, 0, stream>>>(x, Wt, Q, K, V);
    vtrans_kernel<<<dim3(32, 48), 256, 0, stream>>>(V, Vt);
    attn_kernel<<<dim3(16, 48), 256, 0, stream>>>(Q, K, Vt, Z);
    out_kernel<<<128, 256, 0, stream>>>(Z, Wot, out);
}